// Round 3
// baseline (105.577 us; speedup 1.0000x reference)
//
#include <hip/hip_runtime.h>

// LDDMM variational evolve: B=1, N=8192, D=3, fp32.
// dmom_i = 2g * (x_i * sum_j w_ij  -  sum_j w_ij x_j),  w_ij = K_ij <p_i,p_j>
// dx_i   = sum_j K_ij p_j,   K_ij = exp(-g |x_i - x_j|^2), g = 100.
//
// Round 6: resurrect r1's scalar-load partial (j-data via SGPR/s_load, no LDS,
// no __syncthreads) which decomposition shows ran ~28-30 us vs ~44 us for the
// LDS-broadcast version -- r1's total regressed only because its merged
// 32-block reduce was BW-starved (29.4 MB / 32 CUs ~= 36 us). This round:
//   - partial: r1 structure, grid (16,128)=2048 blocks = 8/CU,
//     __launch_bounds__(256,8) to cap VGPR <= 64 so all 8 are resident.
//   - reduce: r0's channel-parallel grid (N/TPB, 7) = 224 blocks (~5.5 us).
//   - separate tiny finalize.
// NOTE: ci must stay inside the exponent (arg <= 0 always); factoring
// exp2(ci) out overflows: inner arg reaches +432 -> inf * 0 = NaN.

#define TPB 256
#define ITILE 2
constexpr float GAMMA_C = 100.0f;
constexpr float LOG2E_C = 1.4426950408889634f;
constexpr float SB_C    = 2.0f * GAMMA_C * LOG2E_C;  // A.xyz = SB*x_j
constexpr float SC_C    = -GAMMA_C * LOG2E_C;        // A.w   = SC*|x_j|^2
constexpr float LN2_C   = 0.69314718055994531f;      // 2g/SB

// ---- Kernel 0: pack j-side operands ---------------------------------------
// J[2*j]   = {SB*x, SB*y, SB*z, SC*|x|^2}
// J[2*j+1] = {px, py, pz, 0}
__global__ __launch_bounds__(TPB) void lddmm_prep(
    const float* __restrict__ mom, const float* __restrict__ xpt,
    float4* __restrict__ J, int N) {
  const int i = blockIdx.x * TPB + threadIdx.x;
  if (i >= N) return;
  const float bx = xpt[3*i], by = xpt[3*i+1], bz = xpt[3*i+2];
  J[2*i]   = make_float4(SB_C*bx, SB_C*by, SB_C*bz,
                         SC_C * fmaf(bx, bx, fmaf(by, by, bz*bz)));
  J[2*i+1] = make_float4(mom[3*i], mom[3*i+1], mom[3*i+2], 0.f);
}

// ---- Kernel A: per-segment partial sums ------------------------------------
// grid (N/(TPB*ITILE), SEG). part layout: P[c][s][i], c=0..6, each [SEG][N].
// j-data comes in via uniform (scalar) loads: Jseg + loop index are
// wave-uniform, so hipcc emits s_load_dwordx4/x8 through the constant cache.
// Every inner fma uses <=1 SGPR operand (ISA limit), which all of these do.
__global__ __launch_bounds__(TPB, 8) void lddmm_partial(
    const float* __restrict__ mom, const float* __restrict__ xpt,
    const float4* __restrict__ J,
    float* __restrict__ part, int N, int SEG, int JT) {
  const int tid = threadIdx.x;
  const int seg = blockIdx.y;

  const int i0 = blockIdx.x * (TPB * ITILE) + tid;
  const int i1 = i0 + TPB;

  const float x0 = xpt[3*i0], y0 = xpt[3*i0+1], z0 = xpt[3*i0+2];
  const float p0x = mom[3*i0], p0y = mom[3*i0+1], p0z = mom[3*i0+2];
  const float c0 = SC_C * fmaf(x0, x0, fmaf(y0, y0, z0*z0));
  const float x1 = xpt[3*i1], y1 = xpt[3*i1+1], z1 = xpt[3*i1+2];
  const float p1x = mom[3*i1], p1y = mom[3*i1+1], p1z = mom[3*i1+2];
  const float c1 = SC_C * fmaf(x1, x1, fmaf(y1, y1, z1*z1));

  // uniform base: all lanes (and the whole wave) share this pointer
  const float4* __restrict__ Jseg = J + (size_t)2 * (size_t)seg * (size_t)JT;

  float a0=0.f, wx0=0.f, wy0=0.f, wz0=0.f, gx0=0.f, gy0=0.f, gz0=0.f;
  float a1=0.f, wx1=0.f, wy1=0.f, wz1=0.f, gx1=0.f, gy1=0.f, gz1=0.f;

#pragma unroll 4
  for (int t = 0; t < JT; ++t) {
    const float4 A = Jseg[2*t];       // uniform -> s_load_dwordx4
    const float4 P = Jseg[2*t+1];     // uniform -> s_load_dwordx4
    // i0
    {
      const float arg = fmaf(A.x, x0, fmaf(A.y, y0, fmaf(A.z, z0, c0 + A.w)));
      const float K   = __builtin_amdgcn_exp2f(arg);          // bare v_exp_f32
      const float dot = fmaf(P.x, p0x, fmaf(P.y, p0y, P.z * p0z));
      const float w   = K * dot;
      a0 += w;
      wx0 = fmaf(w, A.x, wx0); wy0 = fmaf(w, A.y, wy0); wz0 = fmaf(w, A.z, wz0);
      gx0 = fmaf(K, P.x, gx0); gy0 = fmaf(K, P.y, gy0); gz0 = fmaf(K, P.z, gz0);
    }
    // i1
    {
      const float arg = fmaf(A.x, x1, fmaf(A.y, y1, fmaf(A.z, z1, c1 + A.w)));
      const float K   = __builtin_amdgcn_exp2f(arg);
      const float dot = fmaf(P.x, p1x, fmaf(P.y, p1y, P.z * p1z));
      const float w   = K * dot;
      a1 += w;
      wx1 = fmaf(w, A.x, wx1); wy1 = fmaf(w, A.y, wy1); wz1 = fmaf(w, A.z, wz1);
      gx1 = fmaf(K, P.x, gx1); gy1 = fmaf(K, P.y, gy1); gz1 = fmaf(K, P.z, gz1);
    }
  }

  const size_t SN = (size_t)SEG * N;
  float* p = part + (size_t)seg * N;
  p[0*SN+i0] = a0;  p[0*SN+i1] = a1;
  p[1*SN+i0] = wx0; p[1*SN+i1] = wx1;
  p[2*SN+i0] = wy0; p[2*SN+i1] = wy1;
  p[3*SN+i0] = wz0; p[3*SN+i1] = wz1;
  p[4*SN+i0] = gx0; p[4*SN+i1] = gx1;
  p[5*SN+i0] = gy0; p[5*SN+i1] = gy1;
  p[6*SN+i0] = gz0; p[6*SN+i1] = gz1;
}

// ---- Kernel B: reduce over segments (parallel over channels) ---------------
__global__ __launch_bounds__(TPB) void lddmm_reduce(
    const float* __restrict__ part, float* __restrict__ R, int N, int SEG) {
  const int i = blockIdx.x * TPB + threadIdx.x;
  const int c = blockIdx.y;
  const float* src = part + (size_t)c * SEG * N + i;
  float s0 = 0.f, s1 = 0.f, s2 = 0.f, s3 = 0.f;
  int s = 0;
  for (; s + 4 <= SEG; s += 4) {
    s0 += src[(size_t)(s+0)*N]; s1 += src[(size_t)(s+1)*N];
    s2 += src[(size_t)(s+2)*N]; s3 += src[(size_t)(s+3)*N];
  }
  for (; s < SEG; ++s) s0 += src[(size_t)s*N];
  R[(size_t)c * N + i] = (s0 + s1) + (s2 + s3);
}

// ---- Kernel C: finalize ----------------------------------------------------
__global__ __launch_bounds__(TPB) void lddmm_finalize(
    const float* __restrict__ R, const float* __restrict__ xpt,
    float* __restrict__ out, int N) {
  const int i = blockIdx.x * TPB + threadIdx.x;
  const float A  = R[i];
  const float WX = R[(size_t)1*N+i], WY = R[(size_t)2*N+i], WZ = R[(size_t)3*N+i];
  const float GX = R[(size_t)4*N+i], GY = R[(size_t)5*N+i], GZ = R[(size_t)6*N+i];
  const float xi = xpt[3*i], yi = xpt[3*i+1], zi = xpt[3*i+2];
  const float TGA = 2.0f * GAMMA_C * A;
  out[3*i+0] = fmaf(TGA, xi, -LN2_C * WX);
  out[3*i+1] = fmaf(TGA, yi, -LN2_C * WY);
  out[3*i+2] = fmaf(TGA, zi, -LN2_C * WZ);
  out[3*N + 3*i + 0] = GX;
  out[3*N + 3*i + 1] = GY;
  out[3*N + 3*i + 2] = GZ;
}

// ---- Fallback (tiny ws): atomic single-kernel version ----------------------
__global__ __launch_bounds__(TPB) void lddmm_atomic(
    const float* __restrict__ mom, const float* __restrict__ xpt,
    float* __restrict__ out, int N) {
  const int i  = blockIdx.x * TPB + threadIdx.x;
  const int jb = blockIdx.y * TPB;
  __shared__ float4 sA[TPB], sP[TPB];
  {
    const int j = jb + threadIdx.x;
    const float bx = xpt[3*j], by = xpt[3*j+1], bz = xpt[3*j+2];
    sA[threadIdx.x] = make_float4(SB_C*bx, SB_C*by, SB_C*bz,
                                  SC_C * fmaf(bx, bx, fmaf(by, by, bz*bz)));
    sP[threadIdx.x] = make_float4(mom[3*j], mom[3*j+1], mom[3*j+2], 0.f);
  }
  __syncthreads();
  const float xi = xpt[3*i], yi = xpt[3*i+1], zi = xpt[3*i+2];
  const float pxi = mom[3*i], pyi = mom[3*i+1], pzi = mom[3*i+2];
  const float ci = SC_C * fmaf(xi, xi, fmaf(yi, yi, zi*zi));
  float a=0.f, wx=0.f, wy=0.f, wz=0.f, gx=0.f, gy=0.f, gz=0.f;
#pragma unroll 4
  for (int t = 0; t < TPB; ++t) {
    const float4 A = sA[t], P = sP[t];
    const float arg = fmaf(A.x, xi, fmaf(A.y, yi, fmaf(A.z, zi, ci + A.w)));
    const float K   = __builtin_amdgcn_exp2f(arg);
    const float dot = fmaf(P.x, pxi, fmaf(P.y, pyi, P.z * pzi));
    const float w   = K * dot;
    a += w;
    wx = fmaf(w, A.x, wx); wy = fmaf(w, A.y, wy); wz = fmaf(w, A.z, wz);
    gx = fmaf(K, P.x, gx); gy = fmaf(K, P.y, gy); gz = fmaf(K, P.z, gz);
  }
  const float TGA = 2.0f * GAMMA_C * a;
  atomicAdd(&out[3*i+0], fmaf(TGA, xi, -LN2_C * wx));
  atomicAdd(&out[3*i+1], fmaf(TGA, yi, -LN2_C * wy));
  atomicAdd(&out[3*i+2], fmaf(TGA, zi, -LN2_C * wz));
  atomicAdd(&out[3*N+3*i+0], gx);
  atomicAdd(&out[3*N+3*i+1], gy);
  atomicAdd(&out[3*N+3*i+2], gz);
}

extern "C" void kernel_launch(void* const* d_in, const int* in_sizes, int n_in,
                              void* d_out, int out_size, void* d_ws, size_t ws_size,
                              hipStream_t stream) {
  const float* mom = (const float*)d_in[0];   // setup_inputs order: mom first
  const float* xpt = (const float*)d_in[1];   // control_points second
  float* out = (float*)d_out;
  const int N = in_sizes[0] / 3;              // 8192

  // ws layout: J (8N floats) | part (7*SEG*N floats) | R (7N floats)
  auto need = [&](int s) { return (size_t)(8 + 7*s + 7) * (size_t)N * sizeof(float); };
  int SEG = 128;
  while (SEG > 2 && need(SEG) > ws_size) SEG >>= 1;

  const bool shapes_ok = (N % (TPB * ITILE) == 0) && (N % SEG == 0);
  if (need(SEG) <= ws_size && shapes_ok) {
    const int JT = N / SEG;                   // 64 @ SEG=128
    float4* Jv   = (float4*)d_ws;
    float* partb = (float*)d_ws + (size_t)8 * N;
    float* R     = partb + (size_t)7 * SEG * N;
    lddmm_prep<<<(N + TPB - 1) / TPB, TPB, 0, stream>>>(mom, xpt, Jv, N);
    dim3 gA(N / (TPB * ITILE), SEG);          // (16, 128) = 2048 blocks, 8/CU
    lddmm_partial<<<gA, TPB, 0, stream>>>(mom, xpt, Jv, partb, N, SEG, JT);
    dim3 gB(N / TPB, 7);                      // 224 blocks — parallel reduce
    lddmm_reduce<<<gB, TPB, 0, stream>>>(partb, R, N, SEG);
    lddmm_finalize<<<N / TPB, TPB, 0, stream>>>(R, xpt, out, N);
  } else {
    hipMemsetAsync(d_out, 0, (size_t)out_size * sizeof(float), stream);
    dim3 grid(N / TPB, N / TPB);
    lddmm_atomic<<<grid, TPB, 0, stream>>>(mom, xpt, out, N);
  }
}

// Round 4
// 100.859 us; speedup vs baseline: 1.0468x; 1.0468x over previous
//
#include <hip/hip_runtime.h>

// LDDMM variational evolve: B=1, N=8192, D=3, fp32.
// dmom_i = 2g * (x_i * sum_j w_ij  -  sum_j w_ij x_j),  w_ij = K_ij <p_i,p_j>
// dx_i   = sum_j K_ij p_j,   K_ij = exp(-g |x_i - x_j|^2), g = 100.
//
// Round 7: packed-FP32 inner loop. Evidence from r0-r3: partial is ~40 us in
// every staging/ILP/occupancy variant -> issue-port-bound (15 VALU + 1 exp
// per pair). MI355X fp32 peak (157 TF) requires v_pk_fma_f32 (VOP3P, 2 fma
// per instr); hipcc won't auto-pack, so the j-loop now processes PAIRS of j
// with packed float2 operands via inline asm: 7.5 pk-ops + 1 exp per pair
// (was 15 VALU + 1 exp). Staging stays LDS-broadcast (proven equivalent to
// scalar loads), ITILE=2, SEG=128, channel-parallel reduce.
// NOTE: ci must stay inside the exponent (arg <= 0 always); factoring
// exp2(ci) out overflows: inner arg reaches +432 -> inf * 0 = NaN.

#define TPB 256
#define ITILE 2
constexpr float GAMMA_C = 100.0f;
constexpr float LOG2E_C = 1.4426950408889634f;
constexpr float SB_C    = 2.0f * GAMMA_C * LOG2E_C;  // Ax,Ay,Az = SB*x_j
constexpr float SC_C    = -GAMMA_C * LOG2E_C;        // Aw = SC*|x_j|^2
constexpr float LN2_C   = 0.69314718055994531f;      // 2g/SB

typedef float v2f __attribute__((ext_vector_type(2)));

static __device__ __forceinline__ v2f pk_fma(v2f a, v2f b, v2f c) {
  v2f d;
  asm("v_pk_fma_f32 %0, %1, %2, %3" : "=v"(d) : "v"(a), "v"(b), "v"(c));
  return d;
}
static __device__ __forceinline__ v2f pk_mul(v2f a, v2f b) {
  v2f d;
  asm("v_pk_mul_f32 %0, %1, %2" : "=v"(d) : "v"(a), "v"(b));
  return d;
}
static __device__ __forceinline__ v2f pk_add(v2f a, v2f b) {
  v2f d;
  asm("v_pk_add_f32 %0, %1, %2" : "=v"(d) : "v"(a), "v"(b));
  return d;
}

// ---- Kernel 0: pack j-side operands into pair-interleaved float4s ----------
// Per pair jp (j0=2jp, j1=2jp+1), 4 float4:
//   [0] = {SB*x0, SB*x1, SB*y0, SB*y1}
//   [1] = {SB*z0, SB*z1, SC*|x0|^2, SC*|x1|^2}
//   [2] = {p0x, p1x, p0y, p1y}
//   [3] = {p0z, p1z, 0, 0}
__global__ __launch_bounds__(TPB) void lddmm_prep(
    const float* __restrict__ mom, const float* __restrict__ xpt,
    float4* __restrict__ J2, int N) {
  const int jp = blockIdx.x * TPB + threadIdx.x;
  if (jp >= N / 2) return;
  const int j0 = 2 * jp, j1 = 2 * jp + 1;
  const float x0 = xpt[3*j0], y0 = xpt[3*j0+1], z0 = xpt[3*j0+2];
  const float x1 = xpt[3*j1], y1 = xpt[3*j1+1], z1 = xpt[3*j1+2];
  const float n0 = SC_C * fmaf(x0, x0, fmaf(y0, y0, z0*z0));
  const float n1 = SC_C * fmaf(x1, x1, fmaf(y1, y1, z1*z1));
  J2[4*jp+0] = make_float4(SB_C*x0, SB_C*x1, SB_C*y0, SB_C*y1);
  J2[4*jp+1] = make_float4(SB_C*z0, SB_C*z1, n0, n1);
  J2[4*jp+2] = make_float4(mom[3*j0], mom[3*j1], mom[3*j0+1], mom[3*j1+1]);
  J2[4*jp+3] = make_float4(mom[3*j0+2], mom[3*j1+2], 0.f, 0.f);
}

// ---- Kernel A: per-segment partial sums (packed fp32) ----------------------
// grid (N/(TPB*ITILE), SEG). part layout: P[c][s][i], c=0..6, each [SEG][N].
__global__ __launch_bounds__(TPB, 4) void lddmm_partial(
    const float* __restrict__ mom, const float* __restrict__ xpt,
    const float4* __restrict__ J2,
    float* __restrict__ part, int N, int SEG, int JT) {
  extern __shared__ float4 sL[];
  const int tid = threadIdx.x;
  const int seg = blockIdx.y;
  const int JP = JT / 2;                       // pairs per segment (32)

  for (int t = tid; t < JP * 4; t += TPB)
    sL[t] = J2[(size_t)seg * JP * 4 + t];
  __syncthreads();

  const int i0 = blockIdx.x * (TPB * ITILE) + tid;

  // i-side values duplicated into both packed halves
  v2f X[ITILE], Y[ITILE], Z[ITILE], C[ITILE];
  v2f PX[ITILE], PY[ITILE], PZ[ITILE];
#pragma unroll
  for (int u = 0; u < ITILE; ++u) {
    const int i = i0 + u * TPB;
    const float x = xpt[3*i], y = xpt[3*i+1], z = xpt[3*i+2];
    const float px = mom[3*i], py = mom[3*i+1], pz = mom[3*i+2];
    const float c = SC_C * fmaf(x, x, fmaf(y, y, z*z));
    X[u] = (v2f){x, x};  Y[u] = (v2f){y, y};  Z[u] = (v2f){z, z};
    C[u] = (v2f){c, c};
    PX[u] = (v2f){px, px}; PY[u] = (v2f){py, py}; PZ[u] = (v2f){pz, pz};
  }

  v2f aA[ITILE], aWX[ITILE], aWY[ITILE], aWZ[ITILE];
  v2f aGX[ITILE], aGY[ITILE], aGZ[ITILE];
#pragma unroll
  for (int u = 0; u < ITILE; ++u) {
    aA[u] = (v2f){0.f, 0.f};
    aWX[u] = (v2f){0.f, 0.f}; aWY[u] = (v2f){0.f, 0.f}; aWZ[u] = (v2f){0.f, 0.f};
    aGX[u] = (v2f){0.f, 0.f}; aGY[u] = (v2f){0.f, 0.f}; aGZ[u] = (v2f){0.f, 0.f};
  }

#pragma unroll 2
  for (int pp = 0; pp < JP; ++pp) {
    const float4 q0 = sL[4*pp+0];   // broadcast reads: conflict-free
    const float4 q1 = sL[4*pp+1];
    const float4 q2 = sL[4*pp+2];
    const float4 q3 = sL[4*pp+3];
    const v2f Ax = (v2f){q0.x, q0.y}, Ay = (v2f){q0.z, q0.w};
    const v2f Az = (v2f){q1.x, q1.y}, Aw = (v2f){q1.z, q1.w};
    const v2f Px = (v2f){q2.x, q2.y}, Py = (v2f){q2.z, q2.w};
    const v2f Pz = (v2f){q3.x, q3.y};
#pragma unroll
    for (int u = 0; u < ITILE; ++u) {
      v2f t = pk_fma(Az, Z[u], Aw);
      t = pk_fma(Ay, Y[u], t);
      t = pk_fma(Ax, X[u], t);
      const v2f arg = pk_add(t, C[u]);
      v2f K;
      K.x = __builtin_amdgcn_exp2f(arg.x);     // bare v_exp_f32
      K.y = __builtin_amdgcn_exp2f(arg.y);
      v2f d = pk_mul(Pz, PZ[u]);
      d = pk_fma(Py, PY[u], d);
      d = pk_fma(Px, PX[u], d);
      const v2f w = pk_mul(K, d);
      aA[u]  = pk_add(aA[u], w);
      aWX[u] = pk_fma(w, Ax, aWX[u]);
      aWY[u] = pk_fma(w, Ay, aWY[u]);
      aWZ[u] = pk_fma(w, Az, aWZ[u]);
      aGX[u] = pk_fma(K, Px, aGX[u]);
      aGY[u] = pk_fma(K, Py, aGY[u]);
      aGZ[u] = pk_fma(K, Pz, aGZ[u]);
    }
  }

  const size_t SN = (size_t)SEG * N;
  float* p = part + (size_t)seg * N;
#pragma unroll
  for (int u = 0; u < ITILE; ++u) {
    const int i = i0 + u * TPB;
    p[0*SN+i] = aA[u].x  + aA[u].y;
    p[1*SN+i] = aWX[u].x + aWX[u].y;
    p[2*SN+i] = aWY[u].x + aWY[u].y;
    p[3*SN+i] = aWZ[u].x + aWZ[u].y;
    p[4*SN+i] = aGX[u].x + aGX[u].y;
    p[5*SN+i] = aGY[u].x + aGY[u].y;
    p[6*SN+i] = aGZ[u].x + aGZ[u].y;
  }
}

// ---- Kernel B: reduce over segments (parallel over channels) ---------------
__global__ __launch_bounds__(TPB) void lddmm_reduce(
    const float* __restrict__ part, float* __restrict__ R, int N, int SEG) {
  const int i = blockIdx.x * TPB + threadIdx.x;
  const int c = blockIdx.y;
  const float* src = part + (size_t)c * SEG * N + i;
  float s0 = 0.f, s1 = 0.f, s2 = 0.f, s3 = 0.f;
  int s = 0;
  for (; s + 4 <= SEG; s += 4) {
    s0 += src[(size_t)(s+0)*N]; s1 += src[(size_t)(s+1)*N];
    s2 += src[(size_t)(s+2)*N]; s3 += src[(size_t)(s+3)*N];
  }
  for (; s < SEG; ++s) s0 += src[(size_t)s*N];
  R[(size_t)c * N + i] = (s0 + s1) + (s2 + s3);
}

// ---- Kernel C: finalize ----------------------------------------------------
__global__ __launch_bounds__(TPB) void lddmm_finalize(
    const float* __restrict__ R, const float* __restrict__ xpt,
    float* __restrict__ out, int N) {
  const int i = blockIdx.x * TPB + threadIdx.x;
  const float A  = R[i];
  const float WX = R[(size_t)1*N+i], WY = R[(size_t)2*N+i], WZ = R[(size_t)3*N+i];
  const float GX = R[(size_t)4*N+i], GY = R[(size_t)5*N+i], GZ = R[(size_t)6*N+i];
  const float xi = xpt[3*i], yi = xpt[3*i+1], zi = xpt[3*i+2];
  const float TGA = 2.0f * GAMMA_C * A;
  out[3*i+0] = fmaf(TGA, xi, -LN2_C * WX);
  out[3*i+1] = fmaf(TGA, yi, -LN2_C * WY);
  out[3*i+2] = fmaf(TGA, zi, -LN2_C * WZ);
  out[3*N + 3*i + 0] = GX;
  out[3*N + 3*i + 1] = GY;
  out[3*N + 3*i + 2] = GZ;
}

// ---- Fallback (tiny ws): atomic single-kernel version ----------------------
__global__ __launch_bounds__(TPB) void lddmm_atomic(
    const float* __restrict__ mom, const float* __restrict__ xpt,
    float* __restrict__ out, int N) {
  const int i  = blockIdx.x * TPB + threadIdx.x;
  const int jb = blockIdx.y * TPB;
  __shared__ float4 sA[TPB], sP[TPB];
  {
    const int j = jb + threadIdx.x;
    const float bx = xpt[3*j], by = xpt[3*j+1], bz = xpt[3*j+2];
    sA[threadIdx.x] = make_float4(SB_C*bx, SB_C*by, SB_C*bz,
                                  SC_C * fmaf(bx, bx, fmaf(by, by, bz*bz)));
    sP[threadIdx.x] = make_float4(mom[3*j], mom[3*j+1], mom[3*j+2], 0.f);
  }
  __syncthreads();
  const float xi = xpt[3*i], yi = xpt[3*i+1], zi = xpt[3*i+2];
  const float pxi = mom[3*i], pyi = mom[3*i+1], pzi = mom[3*i+2];
  const float ci = SC_C * fmaf(xi, xi, fmaf(yi, yi, zi*zi));
  float a=0.f, wx=0.f, wy=0.f, wz=0.f, gx=0.f, gy=0.f, gz=0.f;
#pragma unroll 4
  for (int t = 0; t < TPB; ++t) {
    const float4 A = sA[t], P = sP[t];
    const float arg = fmaf(A.x, xi, fmaf(A.y, yi, fmaf(A.z, zi, ci + A.w)));
    const float K   = __builtin_amdgcn_exp2f(arg);
    const float dot = fmaf(P.x, pxi, fmaf(P.y, pyi, P.z * pzi));
    const float w   = K * dot;
    a += w;
    wx = fmaf(w, A.x, wx); wy = fmaf(w, A.y, wy); wz = fmaf(w, A.z, wz);
    gx = fmaf(K, P.x, gx); gy = fmaf(K, P.y, gy); gz = fmaf(K, P.z, gz);
  }
  const float TGA = 2.0f * GAMMA_C * a;
  atomicAdd(&out[3*i+0], fmaf(TGA, xi, -LN2_C * wx));
  atomicAdd(&out[3*i+1], fmaf(TGA, yi, -LN2_C * wy));
  atomicAdd(&out[3*i+2], fmaf(TGA, zi, -LN2_C * wz));
  atomicAdd(&out[3*N+3*i+0], gx);
  atomicAdd(&out[3*N+3*i+1], gy);
  atomicAdd(&out[3*N+3*i+2], gz);
}

extern "C" void kernel_launch(void* const* d_in, const int* in_sizes, int n_in,
                              void* d_out, int out_size, void* d_ws, size_t ws_size,
                              hipStream_t stream) {
  const float* mom = (const float*)d_in[0];   // setup_inputs order: mom first
  const float* xpt = (const float*)d_in[1];   // control_points second
  float* out = (float*)d_out;
  const int N = in_sizes[0] / 3;              // 8192

  // ws layout: J2 (2N float4 = 8N floats) | part (7*SEG*N) | R (7N)
  auto need = [&](int s) { return (size_t)(8 + 7*s + 7) * (size_t)N * sizeof(float); };
  int SEG = 128;
  while (SEG > 2 && need(SEG) > ws_size) SEG >>= 1;

  const int JT = N / SEG;
  const bool shapes_ok = (N % (TPB * ITILE) == 0) && (N % SEG == 0) &&
                         (JT % 2 == 0) && (N % 2 == 0);
  if (need(SEG) <= ws_size && shapes_ok) {
    const int JP = JT / 2;                    // 32 pairs @ SEG=128
    float4* J2   = (float4*)d_ws;
    float* partb = (float*)d_ws + (size_t)8 * N;
    float* R     = partb + (size_t)7 * SEG * N;
    lddmm_prep<<<(N/2 + TPB - 1) / TPB, TPB, 0, stream>>>(mom, xpt, J2, N);
    const size_t shmem = (size_t)JP * 4 * sizeof(float4);   // 2 KB @ JT=64
    dim3 gA(N / (TPB * ITILE), SEG);          // (16, 128) = 2048 blocks
    lddmm_partial<<<gA, TPB, shmem, stream>>>(mom, xpt, J2, partb, N, SEG, JT);
    dim3 gB(N / TPB, 7);                      // 224 blocks — parallel reduce
    lddmm_reduce<<<gB, TPB, 0, stream>>>(partb, R, N, SEG);
    lddmm_finalize<<<N / TPB, TPB, 0, stream>>>(R, xpt, out, N);
  } else {
    hipMemsetAsync(d_out, 0, (size_t)out_size * sizeof(float), stream);
    dim3 grid(N / TPB, N / TPB);
    lddmm_atomic<<<grid, TPB, 0, stream>>>(mom, xpt, out, N);
  }
}